// Round 1
// baseline (2655.646 us; speedup 1.0000x reference)
//
#include <hip/hip_runtime.h>
#include <hip/hip_bf16.h>

// Problem constants
#define B_SZ 2
#define S_LEN 4096
#define D_MODEL 2048
#define NH 16
#define DKH 128
#define CHUNK 32
#define VBLK 32
#define GEMM_M 8192
#define GEMM_N 2048
#define GEMM_K 2048

typedef __bf16 bf16x8 __attribute__((ext_vector_type(8)));
typedef float f32x4 __attribute__((ext_vector_type(4)));

__device__ inline float bf2f(unsigned short u) {
  unsigned int x = ((unsigned int)u) << 16;
  return __builtin_bit_cast(float, x);
}
__device__ inline unsigned short f2bf(float f) {
  __hip_bfloat16 h = __float2bfloat16(f);  // RNE
  return __builtin_bit_cast(unsigned short, h);
}

// ---------------- cast x (f32 -> bf16) ----------------
__global__ __launch_bounds__(256) void cast_bf16_kernel(const float* __restrict__ in,
                                                        unsigned short* __restrict__ out,
                                                        int nvec8) {
  int i = blockIdx.x * 256 + threadIdx.x;
  if (i >= nvec8) return;
  const float4* p = (const float4*)in + (size_t)i * 2;
  float4 a = p[0], b = p[1];
  uint4 o;
  o.x = (unsigned)f2bf(a.x) | ((unsigned)f2bf(a.y) << 16);
  o.y = (unsigned)f2bf(a.z) | ((unsigned)f2bf(a.w) << 16);
  o.z = (unsigned)f2bf(b.x) | ((unsigned)f2bf(b.y) << 16);
  o.w = (unsigned)f2bf(b.z) | ((unsigned)f2bf(b.w) << 16);
  ((uint4*)out)[i] = o;
}

// ---------------- W (f32 [K][N]) -> Wt (bf16 [N][K]) ----------------
__global__ __launch_bounds__(256) void transpose_cast_kernel(const float* __restrict__ W,
                                                             unsigned short* __restrict__ Wt) {
  __shared__ float tile[64][65];
  const int n0 = blockIdx.x * 64, k0 = blockIdx.y * 64;
  for (int jj = 0; jj < 16; ++jj) {
    int flat = threadIdx.x + jj * 256;
    int r = flat >> 6, c = flat & 63;
    tile[r][c] = W[(size_t)(k0 + r) * D_MODEL + n0 + c];
  }
  __syncthreads();
  for (int jj = 0; jj < 16; ++jj) {
    int flat = threadIdx.x + jj * 256;
    int rr = flat >> 6, cc = flat & 63;
    Wt[(size_t)(n0 + rr) * D_MODEL + k0 + cc] = f2bf(tile[cc][rr]);
  }
}

// ---------------- async global->LDS (16B per lane, wave-uniform LDS base) ----------------
__device__ inline void async16(void* lds_dst, const void* gsrc) {
  __builtin_amdgcn_global_load_lds((__attribute__((address_space(1))) void*)(void*)gsrc,
                                   (__attribute__((address_space(3))) void*)lds_dst,
                                   16, 0, 0);
}

// ---------------- bf16 MFMA GEMM: C[M][N] = A[M][K] @ Bt[N][K]^T ----------------
// MODE 0: store bf16 | 1: *DK^-0.5, bf16 | 2: log_sigmoid/16, f32 | 3: store f32
template <int MODE>
__global__ __launch_bounds__(256) void gemm_bt(const unsigned short* __restrict__ A,
                                               const unsigned short* __restrict__ Bt,
                                               void* __restrict__ Cout) {
  __shared__ unsigned short As[128 * 32];
  __shared__ unsigned short Bs[128 * 32];
  const int tid = threadIdx.x;
  const int lane = tid & 63, w = tid >> 6;
  const int bm = blockIdx.y * 128, bn = blockIdx.x * 128;
  const int wm = w >> 1, wn = w & 1;
  const int lr = lane & 15, lg = lane >> 4;

  f32x4 acc[4][4] = {};

  const int srow = (lane >> 2);        // row-within-16 for staging
  const int scol = (lane & 3) * 8;     // k element offset for staging

  for (int kk = 0; kk < GEMM_K; kk += 32) {
    // stage A,B tiles: each wave stages 32 rows of each (2 x 16-row instr)
    async16(&As[(w * 32 + 0) * 32],
            &A[(size_t)(bm + w * 32 + 0 + srow) * GEMM_K + kk + scol]);
    async16(&As[(w * 32 + 16) * 32],
            &A[(size_t)(bm + w * 32 + 16 + srow) * GEMM_K + kk + scol]);
    async16(&Bs[(w * 32 + 0) * 32],
            &Bt[(size_t)(bn + w * 32 + 0 + srow) * GEMM_K + kk + scol]);
    async16(&Bs[(w * 32 + 16) * 32],
            &Bt[(size_t)(bn + w * 32 + 16 + srow) * GEMM_K + kk + scol]);
    __syncthreads();

    bf16x8 af[4], bfr[4];
#pragma unroll
    for (int mi = 0; mi < 4; ++mi)
      af[mi] = *(const bf16x8*)&As[(wm * 64 + mi * 16 + lr) * 32 + lg * 8];
#pragma unroll
    for (int nj = 0; nj < 4; ++nj)
      bfr[nj] = *(const bf16x8*)&Bs[(wn * 64 + nj * 16 + lr) * 32 + lg * 8];
#pragma unroll
    for (int mi = 0; mi < 4; ++mi)
#pragma unroll
      for (int nj = 0; nj < 4; ++nj)
        acc[mi][nj] = __builtin_amdgcn_mfma_f32_16x16x32_bf16(af[mi], bfr[nj], acc[mi][nj], 0, 0, 0);
    __syncthreads();
  }

  // epilogue: D lane mapping (verified): col = lane&15, row = (lane>>4)*4 + reg
#pragma unroll
  for (int mi = 0; mi < 4; ++mi) {
#pragma unroll
    for (int nj = 0; nj < 4; ++nj) {
#pragma unroll
      for (int r = 0; r < 4; ++r) {
        int row = bm + wm * 64 + mi * 16 + lg * 4 + r;
        int col = bn + wn * 64 + nj * 16 + lr;
        float v = acc[mi][nj][r];
        size_t idx = (size_t)row * GEMM_N + col;
        if constexpr (MODE == 0) {
          ((unsigned short*)Cout)[idx] = f2bf(v);
        } else if constexpr (MODE == 1) {
          ((unsigned short*)Cout)[idx] = f2bf(v * 0.08838834764831845f);
        } else if constexpr (MODE == 2) {
          // log_sigmoid(v)/16, numerically safe
          float ls = fminf(v, 0.f) - log1pf(expf(-fabsf(v)));
          ((float*)Cout)[idx] = ls * 0.0625f;
        } else {
          ((float*)Cout)[idx] = v;
        }
      }
    }
  }
}

// ---------------- chunked GLA recurrence ----------------
// grid: (DV/VBLK=4, H=16, B=2); 256 threads.
// State S[k][v] kept as Ssh[v][k] (f32, padded row stride 132).
__global__ __launch_bounds__(256) void gla_chunk(const unsigned short* __restrict__ qb,
                                                 const unsigned short* __restrict__ kb,
                                                 const unsigned short* __restrict__ vb,
                                                 const float* __restrict__ gkf,
                                                 unsigned short* __restrict__ ob) {
  const int tid = threadIdx.x;
  const int vblk = blockIdx.x, h = blockIdx.y, b = blockIdx.z;

  __shared__ float Ssh[VBLK * 132];            // state, [v][k] padded
  __shared__ unsigned short qt[CHUNK * 136];   // q~ (bf16), padded
  __shared__ unsigned short kt[CHUNK * 136];   // k~ (bf16), padded
  __shared__ float vt[CHUNK * VBLK];           // v (f32)
  __shared__ float gkt[CHUNK * 128];           // staged gk
  __shared__ float Ash[CHUNK * CHUNK];         // intra-chunk attention (lower tri)
  __shared__ float EGC[128];                   // exp of chunk-total decay

  for (int i = tid; i < VBLK * 132; i += 256) Ssh[i] = 0.f;

  const size_t rb = (size_t)b * S_LEN;
  const int colQ = h * DKH;
  const int colV = h * DKH + vblk * VBLK;

  for (int c = 0; c < S_LEN / CHUNK; ++c) {
    const int t0 = c * CHUNK;
    __syncthreads();  // prev update done before restaging

    // ---- stage gk (f32), q,k (bf16), v (f32) ----
#pragma unroll
    for (int j = 0; j < 4; ++j) {
      int e = (tid + j * 256) * 4;
      int t = e >> 7, k = e & 127;
      *(float4*)&gkt[t * 128 + k] = *(const float4*)&gkf[(rb + t0 + t) * D_MODEL + colQ + k];
    }
#pragma unroll
    for (int j = 0; j < 2; ++j) {
      int e = (tid + j * 256) * 8;
      int t = e >> 7, k = e & 127;
      *(uint4*)&qt[t * 136 + k] = *(const uint4*)&qb[(rb + t0 + t) * D_MODEL + colQ + k];
      *(uint4*)&kt[t * 136 + k] = *(const uint4*)&kb[(rb + t0 + t) * D_MODEL + colQ + k];
    }
    if (tid < 128) {
      int e = tid * 8;
      int t = e >> 5, v = e & 31;
      uint4 raw = *(const uint4*)&vb[(rb + t0 + t) * D_MODEL + colV + v];
      const unsigned short* us = (const unsigned short*)&raw;
      float4 lo, hi;
      lo.x = bf2f(us[0]); lo.y = bf2f(us[1]); lo.z = bf2f(us[2]); lo.w = bf2f(us[3]);
      hi.x = bf2f(us[4]); hi.y = bf2f(us[5]); hi.z = bf2f(us[6]); hi.w = bf2f(us[7]);
      *(float4*)&vt[t * VBLK + v] = lo;
      *(float4*)&vt[t * VBLK + v + 4] = hi;
    }
    __syncthreads();

    // ---- cumsum of gk per k; q~ = q*e^G, k~ = k*e^-G (in place) ----
    if (tid < 128) {
      float g = 0.f;
      for (int t = 0; t < CHUNK; ++t) {
        g += gkt[t * 128 + tid];
        float eg = __expf(g);
        float ieg = __expf(-g);
        qt[t * 136 + tid] = f2bf(bf2f(qt[t * 136 + tid]) * eg);
        kt[t * 136 + tid] = f2bf(bf2f(kt[t * 136 + tid]) * ieg);
      }
      EGC[tid] = __expf(g);
    }
    __syncthreads();

    // ---- A[t][tp] = q~[t] . k~[tp]  (tp <= t) ----
    {
      int t = tid >> 3;
#pragma unroll
      for (int j = 0; j < 4; ++j) {
        int tp = (tid & 7) * 4 + j;
        if (tp <= t) {
          float dot = 0.f;
          for (int kk2 = 0; kk2 < 128; kk2 += 8) {
            uint4 qv = *(const uint4*)&qt[t * 136 + kk2];
            uint4 kv = *(const uint4*)&kt[tp * 136 + kk2];
            const unsigned short* qa = (const unsigned short*)&qv;
            const unsigned short* ka = (const unsigned short*)&kv;
#pragma unroll
            for (int i = 0; i < 8; ++i) dot += bf2f(qa[i]) * bf2f(ka[i]);
          }
          Ash[t * CHUNK + tp] = dot;
        }
      }
    }
    __syncthreads();

    // ---- o[t][v] = q~[t] . S_prev[:,v] + sum_{tp<=t} A[t][tp] * v[tp][v] ----
    {
      int v = tid & 31;
      int tg = tid >> 5;
#pragma unroll
      for (int j = 0; j < 4; ++j) {
        int t = tg * 4 + j;
        float o = 0.f;
        for (int kk2 = 0; kk2 < 128; kk2 += 8) {
          uint4 qv = *(const uint4*)&qt[t * 136 + kk2];
          const unsigned short* qa = (const unsigned short*)&qv;
          float4 s0 = *(const float4*)&Ssh[v * 132 + kk2];
          float4 s1 = *(const float4*)&Ssh[v * 132 + kk2 + 4];
          o += bf2f(qa[0]) * s0.x + bf2f(qa[1]) * s0.y + bf2f(qa[2]) * s0.z + bf2f(qa[3]) * s0.w;
          o += bf2f(qa[4]) * s1.x + bf2f(qa[5]) * s1.y + bf2f(qa[6]) * s1.z + bf2f(qa[7]) * s1.w;
        }
        for (int tp = 0; tp <= t; ++tp)
          o += Ash[t * CHUNK + tp] * vt[tp * VBLK + v];
        ob[(rb + t0 + t) * D_MODEL + colV + v] = f2bf(o);
      }
    }
    __syncthreads();

    // ---- S[v][k] = EGC[k] * (S[v][k] + sum_t k~[t][k]*v[t][v]) ----
    {
      int v = tid & 31;
      int k0 = (tid >> 5) * 16;
      float acc2[16];
#pragma unroll
      for (int i = 0; i < 16; ++i) acc2[i] = 0.f;
      for (int tp = 0; tp < CHUNK; ++tp) {
        float vv = vt[tp * VBLK + v];
        uint4 k1 = *(const uint4*)&kt[tp * 136 + k0];
        uint4 k2 = *(const uint4*)&kt[tp * 136 + k0 + 8];
        const unsigned short* ka = (const unsigned short*)&k1;
        const unsigned short* kb2 = (const unsigned short*)&k2;
#pragma unroll
        for (int i = 0; i < 8; ++i) acc2[i] += bf2f(ka[i]) * vv;
#pragma unroll
        for (int i = 0; i < 8; ++i) acc2[8 + i] += bf2f(kb2[i]) * vv;
      }
#pragma unroll
      for (int i = 0; i < 16; ++i) {
        int k = k0 + i;
        Ssh[v * 132 + k] = EGC[k] * (Ssh[v * 132 + k] + acc2[i]);
      }
    }
  }
}

// ---------------- launch ----------------
extern "C" void kernel_launch(void* const* d_in, const int* in_sizes, int n_in,
                              void* d_out, int out_size, void* d_ws, size_t ws_size,
                              hipStream_t stream) {
  const float* x = (const float*)d_in[0];
  const float* W[5] = {(const float*)d_in[1], (const float*)d_in[2], (const float*)d_in[3],
                       (const float*)d_in[4], (const float*)d_in[5]};
  float* out = (float*)d_out;
  char* ws = (char*)d_ws;

  const size_t NTOK = (size_t)B_SZ * S_LEN;          // 8192
  const size_t XBN = NTOK * D_MODEL;                  // 16,777,216 elems
  const size_t DD = (size_t)D_MODEL * D_MODEL;        // 4,194,304 elems

  unsigned short* xb = (unsigned short*)ws;                       // bf16 x (and later o)
  unsigned short* Wt = (unsigned short*)(ws + XBN * 2);           // 5 transposed weights
  unsigned short* qb = (unsigned short*)(ws + XBN * 2 + 5 * DD * 2);
  unsigned short* kb = qb + XBN;
  unsigned short* vb = kb + XBN;
  float* gkf = (float*)(vb + XBN);                                // f32 gk
  unsigned short* ob = xb;                                        // reuse xb space for o

  cast_bf16_kernel<<<dim3((unsigned)(XBN / 8 / 256)), dim3(256), 0, stream>>>(x, xb, (int)(XBN / 8));
  for (int i = 0; i < 5; ++i)
    transpose_cast_kernel<<<dim3(32, 32), dim3(256), 0, stream>>>(W[i], Wt + (size_t)i * DD);

  dim3 gg(GEMM_N / 128, GEMM_M / 128);
  gemm_bt<1><<<gg, 256, 0, stream>>>(xb, Wt + 0 * DD, (void*)qb);   // q (scaled)
  gemm_bt<0><<<gg, 256, 0, stream>>>(xb, Wt + 1 * DD, (void*)kb);   // k
  gemm_bt<0><<<gg, 256, 0, stream>>>(xb, Wt + 2 * DD, (void*)vb);   // v
  gemm_bt<2><<<gg, 256, 0, stream>>>(xb, Wt + 3 * DD, (void*)gkf);  // gk = logsigmoid/16

  gla_chunk<<<dim3(4, NH, B_SZ), dim3(256), 0, stream>>>(qb, kb, vb, gkf, ob);

  gemm_bt<3><<<gg, 256, 0, stream>>>(ob, Wt + 4 * DD, (void*)out);  // final projection, f32
}

// Round 3
// 823.616 us; speedup vs baseline: 3.2244x; 3.2244x over previous
//
#include <hip/hip_runtime.h>
#include <hip/hip_bf16.h>

// Problem constants
#define B_SZ 2
#define S_LEN 4096
#define D_MODEL 2048
#define NH 16
#define DKH 128
#define CHUNK 32
#define SEG 256
#define NSEG 16   /* S_LEN / SEG */
#define NCH 8     /* SEG / CHUNK */
#define GEMM_M 8192
#define GEMM_N 2048
#define GEMM_K 2048

typedef __bf16 bf16x8 __attribute__((ext_vector_type(8)));
typedef float f32x4 __attribute__((ext_vector_type(4)));
typedef unsigned short u16x4 __attribute__((ext_vector_type(4)));
typedef unsigned short u16x8 __attribute__((ext_vector_type(8)));

__device__ inline float bf2f(unsigned short u) {
  unsigned int x = ((unsigned int)u) << 16;
  return __builtin_bit_cast(float, x);
}
__device__ inline unsigned short f2bf(float f) {
  __hip_bfloat16 h = __float2bfloat16(f);  // RNE
  return __builtin_bit_cast(unsigned short, h);
}
__device__ inline unsigned int packhl(float s) {
  unsigned short h = f2bf(s);
  unsigned short l = f2bf(s - bf2f(h));
  return ((unsigned int)h << 16) | (unsigned int)l;
}

// ---------------- cast x (f32 -> bf16) ----------------
__global__ __launch_bounds__(256) void cast_bf16_kernel(const float* __restrict__ in,
                                                        unsigned short* __restrict__ out,
                                                        int nvec8) {
  int i = blockIdx.x * 256 + threadIdx.x;
  if (i >= nvec8) return;
  const float4* p = (const float4*)in + (size_t)i * 2;
  float4 a = p[0], b = p[1];
  uint4 o;
  o.x = (unsigned)f2bf(a.x) | ((unsigned)f2bf(a.y) << 16);
  o.y = (unsigned)f2bf(a.z) | ((unsigned)f2bf(a.w) << 16);
  o.z = (unsigned)f2bf(b.x) | ((unsigned)f2bf(b.y) << 16);
  o.w = (unsigned)f2bf(b.z) | ((unsigned)f2bf(b.w) << 16);
  ((uint4*)out)[i] = o;
}

// ---------------- W (f32 [K][N]) -> Wt (bf16 [N][K]) ----------------
__global__ __launch_bounds__(256) void transpose_cast_kernel(const float* __restrict__ W,
                                                             unsigned short* __restrict__ Wt) {
  __shared__ float tile[64][65];
  const int n0 = blockIdx.x * 64, k0 = blockIdx.y * 64;
  for (int jj = 0; jj < 16; ++jj) {
    int flat = threadIdx.x + jj * 256;
    int r = flat >> 6, c = flat & 63;
    tile[r][c] = W[(size_t)(k0 + r) * D_MODEL + n0 + c];
  }
  __syncthreads();
  for (int jj = 0; jj < 16; ++jj) {
    int flat = threadIdx.x + jj * 256;
    int rr = flat >> 6, cc = flat & 63;
    Wt[(size_t)(n0 + rr) * D_MODEL + k0 + cc] = f2bf(tile[cc][rr]);
  }
}

// ---------------- async global->LDS (16B/lane, wave-uniform LDS base) ----------------
__device__ inline void async16(void* lds_dst, const void* gsrc) {
  __builtin_amdgcn_global_load_lds((__attribute__((address_space(1))) void*)(void*)gsrc,
                                   (__attribute__((address_space(3))) void*)lds_dst,
                                   16, 0, 0);
}

// ---------------- bf16 MFMA GEMM: C[M][N] = A[M][K] @ Bt[N][K]^T ----------------
// MODE 0: store bf16 | 1: *DK^-0.5, bf16 | 2: log_sigmoid/16, bf16 | 3: store f32
template <int MODE>
__global__ __launch_bounds__(256) void gemm_bt(const unsigned short* __restrict__ A,
                                               const unsigned short* __restrict__ Bt,
                                               void* __restrict__ Cout) {
  __shared__ unsigned short As[128 * 32];
  __shared__ unsigned short Bs[128 * 32];
  const int tid = threadIdx.x;
  const int lane = tid & 63, w = tid >> 6;
  const int bm = blockIdx.y * 128, bn = blockIdx.x * 128;
  const int wm = w >> 1, wn = w & 1;
  const int lr = lane & 15, lg = lane >> 4;

  f32x4 acc[4][4] = {};

  const int srow = (lane >> 2);
  const int scol = (lane & 3) * 8;

  for (int kk = 0; kk < GEMM_K; kk += 32) {
    async16(&As[(w * 32 + 0) * 32],
            &A[(size_t)(bm + w * 32 + 0 + srow) * GEMM_K + kk + scol]);
    async16(&As[(w * 32 + 16) * 32],
            &A[(size_t)(bm + w * 32 + 16 + srow) * GEMM_K + kk + scol]);
    async16(&Bs[(w * 32 + 0) * 32],
            &Bt[(size_t)(bn + w * 32 + 0 + srow) * GEMM_K + kk + scol]);
    async16(&Bs[(w * 32 + 16) * 32],
            &Bt[(size_t)(bn + w * 32 + 16 + srow) * GEMM_K + kk + scol]);
    __syncthreads();

    bf16x8 af[4], bfr[4];
#pragma unroll
    for (int mi = 0; mi < 4; ++mi)
      af[mi] = *(const bf16x8*)&As[(wm * 64 + mi * 16 + lr) * 32 + lg * 8];
#pragma unroll
    for (int nj = 0; nj < 4; ++nj)
      bfr[nj] = *(const bf16x8*)&Bs[(wn * 64 + nj * 16 + lr) * 32 + lg * 8];
#pragma unroll
    for (int mi = 0; mi < 4; ++mi)
#pragma unroll
      for (int nj = 0; nj < 4; ++nj)
        acc[mi][nj] = __builtin_amdgcn_mfma_f32_16x16x32_bf16(af[mi], bfr[nj], acc[mi][nj], 0, 0, 0);
    __syncthreads();
  }

#pragma unroll
  for (int mi = 0; mi < 4; ++mi) {
#pragma unroll
    for (int nj = 0; nj < 4; ++nj) {
#pragma unroll
      for (int r = 0; r < 4; ++r) {
        int row = bm + wm * 64 + mi * 16 + lg * 4 + r;
        int col = bn + wn * 64 + nj * 16 + lr;
        float v = acc[mi][nj][r];
        size_t idx = (size_t)row * GEMM_N + col;
        if constexpr (MODE == 0) {
          ((unsigned short*)Cout)[idx] = f2bf(v);
        } else if constexpr (MODE == 1) {
          ((unsigned short*)Cout)[idx] = f2bf(v * 0.08838834764831845f);
        } else if constexpr (MODE == 2) {
          float ls = fminf(v, 0.f) - log1pf(expf(-fabsf(v)));
          ((unsigned short*)Cout)[idx] = f2bf(ls * 0.0625f);
        } else {
          ((float*)Cout)[idx] = v;
        }
      }
    }
  }
}

// =====================================================================
// Pass 1: per-segment local GLA (zero initial state) + segment summaries.
// grid (NSEG, NH, B), 256 threads (4 waves). LDS = 143.4 KB (<160 KB cap).
// Wave w owns state rows k in [32w, 32w+32): sacc[2][8] f32x4, D-layout [k][v].
// NOTE: qhat aliases qb (block-local writes trail its own staged reads).
// =====================================================================
__global__ __launch_bounds__(256) void gla_seg1(
    const unsigned short* qb, const unsigned short* __restrict__ kb,
    const unsigned short* __restrict__ vb, const unsigned short* __restrict__ gkb,
    unsigned short* qhat, unsigned short* __restrict__ obuf,
    float* __restrict__ dS, float* __restrict__ Dseg) {
  __shared__ __align__(16) unsigned short rawq[32 * 128];
  __shared__ __align__(16) unsigned short rawk[32 * 128];
  __shared__ __align__(16) unsigned short rawv[32 * 128];
  __shared__ __align__(16) unsigned short rawg[32 * 128];
  __shared__ __align__(16) unsigned short qt[32 * 136];   // q~ rows t (stride 136)
  __shared__ __align__(16) unsigned short kt[32 * 136];   // k~ rows tp
  __shared__ __align__(16) unsigned short ktT[128 * 40];  // k~^T rows k (t-contig)
  __shared__ __align__(16) unsigned short vT[128 * 40];   // v^T rows v (t-contig)
  __shared__ __align__(16) unsigned short Am[32 * 40];    // masked A rows t (tp-contig)
  __shared__ __align__(16) unsigned short Shi[128 * 136]; // S_old hi, [v][k]
  __shared__ __align__(16) unsigned short Slo[128 * 136]; // S_old lo
  __shared__ __align__(16) float EGC[128];                // e^{G_C}

  const int tid = threadIdx.x;
  const int lane = tid & 63, w = tid >> 6;
  const int lr = lane & 15, lg = lane >> 4;
  const int seg = blockIdx.x, h = blockIdx.y, b = blockIdx.z;
  const int colQ = h * DKH;
  const size_t segtok = (size_t)b * S_LEN + (size_t)seg * SEG;

  f32x4 sacc[2][8] = {};
  float gseg = 0.f;

  auto stage_chunk = [&](int c) {
    const size_t ctok = segtok + c * CHUNK;
    const int r0 = 8 * w;
    const int rr = r0 + (lane >> 4);
    const int cc = (lane & 15) * 8;
    async16(&rawq[(r0) * 128], &qb[(ctok + rr) * D_MODEL + colQ + cc]);
    async16(&rawq[(r0 + 4) * 128], &qb[(ctok + rr + 4) * D_MODEL + colQ + cc]);
    async16(&rawk[(r0) * 128], &kb[(ctok + rr) * D_MODEL + colQ + cc]);
    async16(&rawk[(r0 + 4) * 128], &kb[(ctok + rr + 4) * D_MODEL + colQ + cc]);
    async16(&rawv[(r0) * 128], &vb[(ctok + rr) * D_MODEL + colQ + cc]);
    async16(&rawv[(r0 + 4) * 128], &vb[(ctok + rr + 4) * D_MODEL + colQ + cc]);
    async16(&rawg[(r0) * 128], &gkb[(ctok + rr) * D_MODEL + colQ + cc]);
    async16(&rawg[(r0 + 4) * 128], &gkb[(ctok + rr + 4) * D_MODEL + colQ + cc]);
  };

  stage_chunk(0);

  for (int c = 0; c < NCH; ++c) {
    const size_t ctok = segtok + c * CHUNK;
    __syncthreads();  // staged chunk c ready; prev chunk's LDS reads done

    // ---- PHASE A1: spill S_old (hi/lo bf16) for the o_inter MFMA ----
#pragma unroll
    for (int ktl = 0; ktl < 2; ++ktl) {
      const int k0 = 32 * w + ktl * 16 + lg * 4;
#pragma unroll
      for (int vt = 0; vt < 8; ++vt) {
        const int v = vt * 16 + lr;
        u16x4 hv, lv;
#pragma unroll
        for (int r = 0; r < 4; ++r) {
          float s = sacc[ktl][vt][r];
          unsigned short h_ = f2bf(s);
          hv[r] = h_;
          lv[r] = f2bf(s - bf2f(h_));
        }
        *(u16x4*)&Shi[v * 136 + k0] = hv;
        *(u16x4*)&Slo[v * 136 + k0] = lv;
      }
    }

    // ---- PHASE A2: cumsum+scale (waves 0,1) || v-transpose (waves 2,3) ----
    if (tid < 128) {
      const int k = tid;
      float g = 0.f;
      const float egsp = __expf(gseg);
#pragma unroll
      for (int t = 0; t < CHUNK; ++t) {
        g += bf2f(rawg[t * 128 + k]);
        float eg = __expf(g), ieg = __expf(-g);
        float qv = bf2f(rawq[t * 128 + k]) * eg;
        qt[t * 136 + k] = f2bf(qv);
        qhat[(ctok + t) * D_MODEL + colQ + k] = f2bf(qv * egsp);
        unsigned short kbf = f2bf(bf2f(rawk[t * 128 + k]) * ieg);
        kt[t * 136 + k] = kbf;
        ktT[k * 40 + t] = kbf;
      }
      EGC[k] = __expf(g);
      gseg += g;
    } else {
      const int j = tid - 128;
#pragma unroll
      for (int i = 0; i < 4; ++i) {
        int f = j * 4 + i;  // 0..511 uint4s of rawv
        int t = f >> 4, v0 = (f & 15) * 8;
        u16x8 r8 = *(const u16x8*)&rawv[t * 128 + v0];
#pragma unroll
        for (int e = 0; e < 8; ++e) vT[(v0 + e) * 40 + t] = r8[e];
      }
    }
    __syncthreads();

    if (c + 1 < NCH) stage_chunk(c + 1);  // overlap next-chunk loads with MFMA phases

    // ---- PHASE B: intra-chunk attention A = q~ k~^T (masked) ----
    {
      const int tt = w >> 1, tpt = w & 1;
      if (tpt <= tt) {
        f32x4 aacc = {};
#pragma unroll
        for (int ks = 0; ks < 4; ++ks) {
          bf16x8 qa = *(const bf16x8*)&qt[(tt * 16 + lr) * 136 + ks * 32 + lg * 8];
          bf16x8 ka = *(const bf16x8*)&kt[(tpt * 16 + lr) * 136 + ks * 32 + lg * 8];
          aacc = __builtin_amdgcn_mfma_f32_16x16x32_bf16(qa, ka, aacc, 0, 0, 0);
        }
#pragma unroll
        for (int r = 0; r < 4; ++r) {
          int t = tt * 16 + lg * 4 + r;
          int tp = tpt * 16 + lr;
          Am[t * 40 + tp] = f2bf((tp <= t) ? aacc[r] : 0.f);
        }
      } else {  // w==1: upper tile is all zero
#pragma unroll
        for (int r = 0; r < 4; ++r) Am[(lg * 4 + r) * 40 + 16 + lr] = 0;
      }
    }
    __syncthreads();

    // ---- PHASE C: o = q~@S_old + A@v ; sacc = EGC*(sacc + k~^T@v) ----
    f32x4 oacc[2][2] = {};
#pragma unroll
    for (int ks = 0; ks < 4; ++ks) {
      bf16x8 qa0 = *(const bf16x8*)&qt[(lr) * 136 + ks * 32 + lg * 8];
      bf16x8 qa1 = *(const bf16x8*)&qt[(16 + lr) * 136 + ks * 32 + lg * 8];
#pragma unroll
      for (int vtl = 0; vtl < 2; ++vtl) {
        const int v = (2 * w + vtl) * 16 + lr;
        bf16x8 bh = *(const bf16x8*)&Shi[v * 136 + ks * 32 + lg * 8];
        bf16x8 bl = *(const bf16x8*)&Slo[v * 136 + ks * 32 + lg * 8];
        oacc[0][vtl] = __builtin_amdgcn_mfma_f32_16x16x32_bf16(qa0, bh, oacc[0][vtl], 0, 0, 0);
        oacc[0][vtl] = __builtin_amdgcn_mfma_f32_16x16x32_bf16(qa0, bl, oacc[0][vtl], 0, 0, 0);
        oacc[1][vtl] = __builtin_amdgcn_mfma_f32_16x16x32_bf16(qa1, bh, oacc[1][vtl], 0, 0, 0);
        oacc[1][vtl] = __builtin_amdgcn_mfma_f32_16x16x32_bf16(qa1, bl, oacc[1][vtl], 0, 0, 0);
      }
    }
    {
      bf16x8 am0 = *(const bf16x8*)&Am[(lr) * 40 + lg * 8];
      bf16x8 am1 = *(const bf16x8*)&Am[(16 + lr) * 40 + lg * 8];
#pragma unroll
      for (int vtl = 0; vtl < 2; ++vtl) {
        const int v = (2 * w + vtl) * 16 + lr;
        bf16x8 bv = *(const bf16x8*)&vT[v * 40 + lg * 8];
        oacc[0][vtl] = __builtin_amdgcn_mfma_f32_16x16x32_bf16(am0, bv, oacc[0][vtl], 0, 0, 0);
        oacc[1][vtl] = __builtin_amdgcn_mfma_f32_16x16x32_bf16(am1, bv, oacc[1][vtl], 0, 0, 0);
      }
    }
#pragma unroll
    for (int tt = 0; tt < 2; ++tt)
#pragma unroll
      for (int vtl = 0; vtl < 2; ++vtl) {
        const int v = (2 * w + vtl) * 16 + lr;
#pragma unroll
        for (int r = 0; r < 4; ++r)
          obuf[(ctok + tt * 16 + lg * 4 + r) * D_MODEL + colQ + v] = f2bf(oacc[tt][vtl][r]);
      }
    {
      bf16x8 ak0 = *(const bf16x8*)&ktT[(32 * w + lr) * 40 + lg * 8];
      bf16x8 ak1 = *(const bf16x8*)&ktT[(32 * w + 16 + lr) * 40 + lg * 8];
#pragma unroll
      for (int vt = 0; vt < 8; ++vt) {
        bf16x8 bv = *(const bf16x8*)&vT[(vt * 16 + lr) * 40 + lg * 8];
        sacc[0][vt] = __builtin_amdgcn_mfma_f32_16x16x32_bf16(ak0, bv, sacc[0][vt], 0, 0, 0);
        sacc[1][vt] = __builtin_amdgcn_mfma_f32_16x16x32_bf16(ak1, bv, sacc[1][vt], 0, 0, 0);
      }
      f32x4 eg0 = *(const f32x4*)&EGC[32 * w + lg * 4];
      f32x4 eg1 = *(const f32x4*)&EGC[32 * w + 16 + lg * 4];
#pragma unroll
      for (int vt = 0; vt < 8; ++vt) {
        sacc[0][vt] *= eg0;
        sacc[1][vt] *= eg1;
      }
    }
  }

  // ---- epilogue: write segment summary dS ([v][k] f32) and decay ----
  const size_t dsbase = (((size_t)(b * NH + h) * NSEG + seg) * 128) * 128;
#pragma unroll
  for (int ktl = 0; ktl < 2; ++ktl) {
    const int k0 = 32 * w + ktl * 16 + lg * 4;
#pragma unroll
    for (int vt = 0; vt < 8; ++vt) {
      const int v = vt * 16 + lr;
      float4 st;
      st.x = sacc[ktl][vt][0]; st.y = sacc[ktl][vt][1];
      st.z = sacc[ktl][vt][2]; st.w = sacc[ktl][vt][3];
      *(float4*)&dS[dsbase + (size_t)v * 128 + k0] = st;
    }
  }
  if (tid < 128) Dseg[((size_t)(b * NH + h) * NSEG + seg) * 128 + tid] = __expf(gseg);
}

// =====================================================================
// Pass 2: segment scan. Sinit[0]=0; Sinit[s+1] = Dseg[s]*Sinit[s] + dS[s].
// Overwrites dS IN PLACE with packed (hi<<16|lo) bf16 Sinit per segment.
// Per-thread: read dS slot BEFORE writing packed state to the same slot.
// grid (8, NH, B).
// =====================================================================
__global__ __launch_bounds__(256) void gla_scan(float* dS, const float* __restrict__ Dseg) {
  unsigned int* Spk = (unsigned int*)dS;
  const int tid = threadIdx.x;
  const int vs = blockIdx.x, h = blockIdx.y, b = blockIdx.z;
  const int v = vs * 16 + (tid >> 4);
  const int k0 = (tid & 15) * 8;
  const size_t bh = (size_t)b * NH + h;
  float s[8];
#pragma unroll
  for (int j = 0; j < 8; ++j) s[j] = 0.f;

  for (int sg = 0; sg < NSEG; ++sg) {
    const size_t base = ((bh * NSEG + sg) * 128 + v) * 128 + k0;
    float4 x0 = *(const float4*)&dS[base];
    float4 x1 = *(const float4*)&dS[base + 4];
    const size_t dbase = (bh * NSEG + sg) * 128 + k0;
    float4 d0 = *(const float4*)&Dseg[dbase];
    float4 d1 = *(const float4*)&Dseg[dbase + 4];

    uint4 p0, p1;
    p0.x = packhl(s[0]); p0.y = packhl(s[1]); p0.z = packhl(s[2]); p0.w = packhl(s[3]);
    p1.x = packhl(s[4]); p1.y = packhl(s[5]); p1.z = packhl(s[6]); p1.w = packhl(s[7]);
    *(uint4*)&Spk[base] = p0;
    *(uint4*)&Spk[base + 4] = p1;

    s[0] = d0.x * s[0] + x0.x; s[1] = d0.y * s[1] + x0.y;
    s[2] = d0.z * s[2] + x0.z; s[3] = d0.w * s[3] + x0.w;
    s[4] = d1.x * s[4] + x1.x; s[5] = d1.y * s[5] + x1.y;
    s[6] = d1.z * s[6] + x1.z; s[7] = d1.w * s[7] + x1.w;
  }
}

// =====================================================================
// Pass 3: o += qhat @ Sinit (per segment). grid (NSEG, NH, B). LDS 69.6 KB.
// MFMA C-operand initialized directly from obuf (fused RMW, no LDS staging).
// =====================================================================
__global__ __launch_bounds__(256) void gla_corr(const unsigned short* __restrict__ qhat,
                                                const unsigned int* __restrict__ Spk,
                                                unsigned short* __restrict__ obuf) {
  __shared__ __align__(16) unsigned short Sh[128 * 136];
  __shared__ __align__(16) unsigned short Sl[128 * 136];
  const int tid = threadIdx.x;
  const int lane = tid & 63, w = tid >> 6;
  const int lr = lane & 15, lg = lane >> 4;
  const int seg = blockIdx.x, h = blockIdx.y, b = blockIdx.z;
  const int colQ = h * DKH;
  const size_t segtok = (size_t)b * S_LEN + (size_t)seg * SEG;
  const size_t sbase = (((size_t)(b * NH + h) * NSEG + seg) * 128) * 128;

  // stage + unpack Sinit hi/lo into padded LDS
#pragma unroll
  for (int i = 0; i < 16; ++i) {
    int f = tid + i * 256;                 // 4096 uint4s over [v][k]
    int v = f >> 5, k0 = (f & 31) * 4;
    uint4 p = *(const uint4*)&Spk[sbase + (size_t)v * 128 + k0];
    u16x4 hv, lv;
    hv[0] = (unsigned short)(p.x >> 16); lv[0] = (unsigned short)(p.x & 0xffff);
    hv[1] = (unsigned short)(p.y >> 16); lv[1] = (unsigned short)(p.y & 0xffff);
    hv[2] = (unsigned short)(p.z >> 16); lv[2] = (unsigned short)(p.z & 0xffff);
    hv[3] = (unsigned short)(p.w >> 16); lv[3] = (unsigned short)(p.w & 0xffff);
    *(u16x4*)&Sh[v * 136 + k0] = hv;
    *(u16x4*)&Sl[v * 136 + k0] = lv;
  }
  __syncthreads();

  for (int nt = 0; nt < 4; ++nt) {
    const int ttile = w * 4 + nt;
    const int t = ttile * 16 + lr;
    f32x4 acc8[8];
    // init accumulator from obuf (D frag: col=t=lr-mapped, row r -> v-contig)
#pragma unroll
    for (int vt = 0; vt < 8; ++vt) {
      u16x4 c4 = *(const u16x4*)&obuf[(segtok + t) * D_MODEL + colQ + vt * 16 + lg * 4];
      acc8[vt][0] = bf2f(c4[0]); acc8[vt][1] = bf2f(c4[1]);
      acc8[vt][2] = bf2f(c4[2]); acc8[vt][3] = bf2f(c4[3]);
    }
#pragma unroll
    for (int ks = 0; ks < 4; ++ks) {
      bf16x8 bq = *(const bf16x8*)&qhat[(segtok + t) * D_MODEL + colQ + ks * 32 + lg * 8];
#pragma unroll
      for (int vt = 0; vt < 8; ++vt) {
        bf16x8 ah = *(const bf16x8*)&Sh[(vt * 16 + lr) * 136 + ks * 32 + lg * 8];
        bf16x8 al = *(const bf16x8*)&Sl[(vt * 16 + lr) * 136 + ks * 32 + lg * 8];
        acc8[vt] = __builtin_amdgcn_mfma_f32_16x16x32_bf16(ah, bq, acc8[vt], 0, 0, 0);
        acc8[vt] = __builtin_amdgcn_mfma_f32_16x16x32_bf16(al, bq, acc8[vt], 0, 0, 0);
      }
    }
#pragma unroll
    for (int vt = 0; vt < 8; ++vt) {
      u16x4 pk;
#pragma unroll
      for (int r = 0; r < 4; ++r) pk[r] = f2bf(acc8[vt][r]);
      *(u16x4*)&obuf[(segtok + t) * D_MODEL + colQ + vt * 16 + lg * 4] = pk;
    }
  }
}

// ---------------- launch ----------------
extern "C" void kernel_launch(void* const* d_in, const int* in_sizes, int n_in,
                              void* d_out, int out_size, void* d_ws, size_t ws_size,
                              hipStream_t stream) {
  const float* x = (const float*)d_in[0];
  const float* W[5] = {(const float*)d_in[1], (const float*)d_in[2], (const float*)d_in[3],
                       (const float*)d_in[4], (const float*)d_in[5]};
  float* out = (float*)d_out;
  char* ws = (char*)d_ws;

  const size_t XBN = (size_t)B_SZ * S_LEN * D_MODEL;           // 16,777,216
  const size_t DD = (size_t)D_MODEL * D_MODEL;                  // 4,194,304
  const size_t NSTATE = (size_t)B_SZ * NH * NSEG * 128 * 128;   // 8,388,608

  // Workspace layout: 243.53 MB total (round-1's proven 243.3 MB + 0.26 MB)
  size_t off = 0;
  unsigned short* xb = (unsigned short*)(ws + off); off += XBN * 2;   // x bf16; later obuf
  unsigned short* Wt = (unsigned short*)(ws + off); off += 5 * DD * 2;
  unsigned short* qb = (unsigned short*)(ws + off); off += XBN * 2;   // q; later qhat (aliased)
  unsigned short* kb = (unsigned short*)(ws + off); off += XBN * 2;
  unsigned short* vb = (unsigned short*)(ws + off); off += XBN * 2;
  unsigned short* gkb = (unsigned short*)(ws + off); off += XBN * 2;  // gk bf16
  float* dS = (float*)(ws + off); off += NSTATE * 4;                  // later packed Sinit
  float* Dsg = (float*)(ws + off); off += (size_t)B_SZ * NH * NSEG * 128 * 4;
  unsigned short* obuf = xb;

  cast_bf16_kernel<<<dim3((unsigned)(XBN / 8 / 256)), dim3(256), 0, stream>>>(x, xb, (int)(XBN / 8));
  for (int i = 0; i < 5; ++i)
    transpose_cast_kernel<<<dim3(32, 32), dim3(256), 0, stream>>>(W[i], Wt + (size_t)i * DD);

  dim3 gg(GEMM_N / 128, GEMM_M / 128);
  gemm_bt<1><<<gg, 256, 0, stream>>>(xb, Wt + 0 * DD, (void*)qb);   // q (scaled)
  gemm_bt<0><<<gg, 256, 0, stream>>>(xb, Wt + 1 * DD, (void*)kb);   // k
  gemm_bt<0><<<gg, 256, 0, stream>>>(xb, Wt + 2 * DD, (void*)vb);   // v
  gemm_bt<2><<<gg, 256, 0, stream>>>(xb, Wt + 3 * DD, (void*)gkb);  // gk (bf16)

  gla_seg1<<<dim3(NSEG, NH, B_SZ), 256, 0, stream>>>(qb, kb, vb, gkb, qb /*qhat*/, obuf, dS, Dsg);
  gla_scan<<<dim3(8, NH, B_SZ), 256, 0, stream>>>(dS, Dsg);
  gla_corr<<<dim3(NSEG, NH, B_SZ), 256, 0, stream>>>(qb /*qhat*/, (const unsigned int*)dS, obuf);

  gemm_bt<3><<<gg, 256, 0, stream>>>(obuf, Wt + 4 * DD, (void*)out);  // final projection
}

// Round 4
// 704.165 us; speedup vs baseline: 3.7713x; 1.1696x over previous
//
#include <hip/hip_runtime.h>
#include <hip/hip_bf16.h>

// Problem constants
#define B_SZ 2
#define S_LEN 4096
#define D_MODEL 2048
#define NH 16
#define DKH 128
#define CHUNK 32
#define SEG 256
#define NSEG 16   /* S_LEN / SEG */
#define NCH 8     /* SEG / CHUNK */
#define GEMM_M 8192
#define GEMM_N 2048
#define GEMM_K 2048
#define NKT 32    /* GEMM_K / 64 */

typedef __bf16 bf16x8 __attribute__((ext_vector_type(8)));
typedef float f32x4 __attribute__((ext_vector_type(4)));
typedef unsigned short u16x4 __attribute__((ext_vector_type(4)));
typedef unsigned short u16x8 __attribute__((ext_vector_type(8)));

__device__ inline float bf2f(unsigned short u) {
  unsigned int x = ((unsigned int)u) << 16;
  return __builtin_bit_cast(float, x);
}
__device__ inline unsigned short f2bf(float f) {
  __hip_bfloat16 h = __float2bfloat16(f);  // RNE
  return __builtin_bit_cast(unsigned short, h);
}
__device__ inline unsigned int packhl(float s) {
  unsigned short h = f2bf(s);
  unsigned short l = f2bf(s - bf2f(h));
  return ((unsigned int)h << 16) | (unsigned int)l;
}

// ---------------- cast x (f32 -> bf16) ----------------
__global__ __launch_bounds__(256) void cast_bf16_kernel(const float* __restrict__ in,
                                                        unsigned short* __restrict__ out,
                                                        int nvec8) {
  int i = blockIdx.x * 256 + threadIdx.x;
  if (i >= nvec8) return;
  const float4* p = (const float4*)in + (size_t)i * 2;
  float4 a = p[0], b = p[1];
  uint4 o;
  o.x = (unsigned)f2bf(a.x) | ((unsigned)f2bf(a.y) << 16);
  o.y = (unsigned)f2bf(a.z) | ((unsigned)f2bf(a.w) << 16);
  o.z = (unsigned)f2bf(b.x) | ((unsigned)f2bf(b.y) << 16);
  o.w = (unsigned)f2bf(b.z) | ((unsigned)f2bf(b.w) << 16);
  ((uint4*)out)[i] = o;
}

// ---------------- W (f32 [K][N]) -> Wt (bf16 [N][K]) ----------------
__global__ __launch_bounds__(256) void transpose_cast_kernel(const float* __restrict__ W,
                                                             unsigned short* __restrict__ Wt) {
  __shared__ float tile[64][65];
  const int n0 = blockIdx.x * 64, k0 = blockIdx.y * 64;
  for (int jj = 0; jj < 16; ++jj) {
    int flat = threadIdx.x + jj * 256;
    int r = flat >> 6, c = flat & 63;
    tile[r][c] = W[(size_t)(k0 + r) * D_MODEL + n0 + c];
  }
  __syncthreads();
  for (int jj = 0; jj < 16; ++jj) {
    int flat = threadIdx.x + jj * 256;
    int rr = flat >> 6, cc = flat & 63;
    Wt[(size_t)(n0 + rr) * D_MODEL + k0 + cc] = f2bf(tile[cc][rr]);
  }
}

// ---------------- async global->LDS (16B/lane, wave-uniform LDS base) ----------------
__device__ __forceinline__ void async16(void* lds_dst, const void* gsrc) {
  __builtin_amdgcn_global_load_lds((__attribute__((address_space(1))) void*)(void*)gsrc,
                                   (__attribute__((address_space(3))) void*)lds_dst,
                                   16, 0, 0);
}

__device__ __forceinline__ void memfence_compiler() { asm volatile("" ::: "memory"); }

// =====================================================================
// 256x256-tile bf16 MFMA GEMM, counted-vmcnt pipeline (T2+T3+T4+T5).
// C[M][N] = A[M][K] @ Bt[N][K]^T.  512 threads (8 waves: 2M x 4N).
// LDS: 2 x (256x64 A + 256x64 B) = 128 KiB, double-buffered per K-tile.
// Swizzle: 16B slot s at row r holds global slot s^(r&7)  (involution;
// applied on the global SOURCE address, read back with the same XOR).
// Schedule per K-tile: {ds_read 24 b128 -> 64 MFMA} ; raw barrier ;
// stage tile t+2 into freed buffer ; s_waitcnt vmcnt(8) ; raw barrier.
// vmcnt never drains to 0 in the main loop (loads span barriers).
// MODE 0: bf16 | 1: *DK^-0.5 bf16 | 2: logsigmoid/16 bf16 | 3: f32
// =====================================================================
__device__ __forceinline__ void stage_tile(const unsigned short* __restrict__ G,
                                           int row0, int k0,
                                           unsigned short* lds_buf, int tid) {
  const int r = tid >> 3;                       // row 0..63 within issue
  const int ssw = ((tid & 7) ^ (r & 7)) * 8;    // pre-swizzled source slot
  const unsigned short* src = &G[(size_t)(row0 + r) * GEMM_K + k0 + ssw];
  char* dst = (char*)lds_buf + (tid >> 6) * 1024;  // wave-uniform base
#pragma unroll
  for (int j = 0; j < 4; ++j)
    async16(dst + j * 8192, src + (size_t)j * 64 * GEMM_K);
}

template <int MODE>
__global__ __launch_bounds__(512, 2) void gemm256(const unsigned short* __restrict__ A,
                                                  const unsigned short* __restrict__ Bt,
                                                  void* __restrict__ Cout) {
  __shared__ unsigned short As[2][256 * 64];
  __shared__ unsigned short Bs[2][256 * 64];
  const int tid = threadIdx.x;
  const int lane = tid & 63;
  const int wid = tid >> 6;
  const int wm = wid >> 2, wn = wid & 3;        // wave grid 2M x 4N
  const int lr = lane & 15, lg = lane >> 4;

  // XCD-aware block swizzle: 256 blocks, 8 XCDs, 32 contiguous per XCD
  const int lid = blockIdx.y * 8 + blockIdx.x;
  const int swz = (lid & 7) * 32 + (lid >> 3);
  const int bm = (swz >> 3) * 256;
  const int bn = (swz & 7) * 256;

  f32x4 acc[8][4] = {};

  // prologue: stage tiles 0 and 1
  stage_tile(A, bm, 0, As[0], tid);
  stage_tile(Bt, bn, 0, Bs[0], tid);
  stage_tile(A, bm, 64, As[1], tid);
  stage_tile(Bt, bn, 64, Bs[1], tid);
  asm volatile("s_waitcnt vmcnt(8)" ::: "memory");   // tile 0 landed
  __builtin_amdgcn_s_barrier();
  __builtin_amdgcn_sched_barrier(0);
  memfence_compiler();

  for (int t = 0; t < NKT; ++t) {
    const int cur = t & 1;
    const unsigned short* Ac = As[cur];
    const unsigned short* Bc = Bs[cur];
#pragma unroll
    for (int ks = 0; ks < 2; ++ks) {
      bf16x8 av[8], bv[4];
      const int slot = ((ks << 2) | lg) ^ (lr & 7);
#pragma unroll
      for (int mi = 0; mi < 8; ++mi)
        av[mi] = *(const bf16x8*)&Ac[(wm * 128 + mi * 16 + lr) * 64 + slot * 8];
#pragma unroll
      for (int nj = 0; nj < 4; ++nj)
        bv[nj] = *(const bf16x8*)&Bc[(wn * 64 + nj * 16 + lr) * 64 + slot * 8];
      __builtin_amdgcn_s_setprio(1);
#pragma unroll
      for (int mi = 0; mi < 8; ++mi)
#pragma unroll
        for (int nj = 0; nj < 4; ++nj)
          acc[mi][nj] = __builtin_amdgcn_mfma_f32_16x16x32_bf16(av[mi], bv[nj], acc[mi][nj], 0, 0, 0);
      __builtin_amdgcn_s_setprio(0);
    }
    // all waves done reading buf[cur]
    memfence_compiler();
    __builtin_amdgcn_s_barrier();
    __builtin_amdgcn_sched_barrier(0);
    if (t + 2 < NKT) {
      stage_tile(A, bm, (t + 2) * 64, As[cur], tid);
      stage_tile(Bt, bn, (t + 2) * 64, Bs[cur], tid);
      asm volatile("s_waitcnt vmcnt(8)" ::: "memory");  // tile t+1 landed
    } else {
      asm volatile("s_waitcnt vmcnt(0)" ::: "memory");  // epilogue drain
    }
    __builtin_amdgcn_s_barrier();
    __builtin_amdgcn_sched_barrier(0);
    memfence_compiler();
  }

  // epilogue: D mapping col=lane&15 (N), row=(lane>>4)*4+r (M)
#pragma unroll
  for (int mi = 0; mi < 8; ++mi) {
#pragma unroll
    for (int nj = 0; nj < 4; ++nj) {
#pragma unroll
      for (int r = 0; r < 4; ++r) {
        int row = bm + wm * 128 + mi * 16 + lg * 4 + r;
        int col = bn + wn * 64 + nj * 16 + lr;
        float v = acc[mi][nj][r];
        size_t idx = (size_t)row * GEMM_N + col;
        if constexpr (MODE == 0) {
          ((unsigned short*)Cout)[idx] = f2bf(v);
        } else if constexpr (MODE == 1) {
          ((unsigned short*)Cout)[idx] = f2bf(v * 0.08838834764831845f);
        } else if constexpr (MODE == 2) {
          float ls = fminf(v, 0.f) - log1pf(expf(-fabsf(v)));
          ((unsigned short*)Cout)[idx] = f2bf(ls * 0.0625f);
        } else {
          ((float*)Cout)[idx] = v;
        }
      }
    }
  }
}

// =====================================================================
// Pass 1: per-segment local GLA (zero initial state) + segment summaries.
// grid (NSEG, NH, B), 256 threads (4 waves). LDS = 143.4 KB (<160 KB cap).
// Wave w owns state rows k in [32w, 32w+32): sacc[2][8] f32x4, D-layout [k][v].
// NOTE: qhat aliases qb (block-local writes trail its own staged reads).
// =====================================================================
__global__ __launch_bounds__(256) void gla_seg1(
    const unsigned short* qb, const unsigned short* __restrict__ kb,
    const unsigned short* __restrict__ vb, const unsigned short* __restrict__ gkb,
    unsigned short* qhat, unsigned short* __restrict__ obuf,
    float* __restrict__ dS, float* __restrict__ Dseg) {
  __shared__ __align__(16) unsigned short rawq[32 * 128];
  __shared__ __align__(16) unsigned short rawk[32 * 128];
  __shared__ __align__(16) unsigned short rawv[32 * 128];
  __shared__ __align__(16) unsigned short rawg[32 * 128];
  __shared__ __align__(16) unsigned short qt[32 * 136];   // q~ rows t (stride 136)
  __shared__ __align__(16) unsigned short kt[32 * 136];   // k~ rows tp
  __shared__ __align__(16) unsigned short ktT[128 * 40];  // k~^T rows k (t-contig)
  __shared__ __align__(16) unsigned short vT[128 * 40];   // v^T rows v (t-contig)
  __shared__ __align__(16) unsigned short Am[32 * 40];    // masked A rows t (tp-contig)
  __shared__ __align__(16) unsigned short Shi[128 * 136]; // S_old hi, [v][k]
  __shared__ __align__(16) unsigned short Slo[128 * 136]; // S_old lo
  __shared__ __align__(16) float EGC[128];                // e^{G_C}

  const int tid = threadIdx.x;
  const int lane = tid & 63, w = tid >> 6;
  const int lr = lane & 15, lg = lane >> 4;
  const int seg = blockIdx.x, h = blockIdx.y, b = blockIdx.z;
  const int colQ = h * DKH;
  const size_t segtok = (size_t)b * S_LEN + (size_t)seg * SEG;

  f32x4 sacc[2][8] = {};
  float gseg = 0.f;

  auto stage_chunk = [&](int c) {
    const size_t ctok = segtok + c * CHUNK;
    const int r0 = 8 * w;
    const int rr = r0 + (lane >> 4);
    const int cc = (lane & 15) * 8;
    async16(&rawq[(r0) * 128], &qb[(ctok + rr) * D_MODEL + colQ + cc]);
    async16(&rawq[(r0 + 4) * 128], &qb[(ctok + rr + 4) * D_MODEL + colQ + cc]);
    async16(&rawk[(r0) * 128], &kb[(ctok + rr) * D_MODEL + colQ + cc]);
    async16(&rawk[(r0 + 4) * 128], &kb[(ctok + rr + 4) * D_MODEL + colQ + cc]);
    async16(&rawv[(r0) * 128], &vb[(ctok + rr) * D_MODEL + colQ + cc]);
    async16(&rawv[(r0 + 4) * 128], &vb[(ctok + rr + 4) * D_MODEL + colQ + cc]);
    async16(&rawg[(r0) * 128], &gkb[(ctok + rr) * D_MODEL + colQ + cc]);
    async16(&rawg[(r0 + 4) * 128], &gkb[(ctok + rr + 4) * D_MODEL + colQ + cc]);
  };

  stage_chunk(0);

  for (int c = 0; c < NCH; ++c) {
    const size_t ctok = segtok + c * CHUNK;
    __syncthreads();  // staged chunk c ready; prev chunk's LDS reads done

    // ---- PHASE A1: spill S_old (hi/lo bf16) for the o_inter MFMA ----
#pragma unroll
    for (int ktl = 0; ktl < 2; ++ktl) {
      const int k0 = 32 * w + ktl * 16 + lg * 4;
#pragma unroll
      for (int vt = 0; vt < 8; ++vt) {
        const int v = vt * 16 + lr;
        u16x4 hv, lv;
#pragma unroll
        for (int r = 0; r < 4; ++r) {
          float s = sacc[ktl][vt][r];
          unsigned short h_ = f2bf(s);
          hv[r] = h_;
          lv[r] = f2bf(s - bf2f(h_));
        }
        *(u16x4*)&Shi[v * 136 + k0] = hv;
        *(u16x4*)&Slo[v * 136 + k0] = lv;
      }
    }

    // ---- PHASE A2: cumsum+scale (waves 0,1) || v-transpose (waves 2,3) ----
    if (tid < 128) {
      const int k = tid;
      float g = 0.f;
      const float egsp = __expf(gseg);
#pragma unroll
      for (int t = 0; t < CHUNK; ++t) {
        g += bf2f(rawg[t * 128 + k]);
        float eg = __expf(g), ieg = __expf(-g);
        float qv = bf2f(rawq[t * 128 + k]) * eg;
        qt[t * 136 + k] = f2bf(qv);
        qhat[(ctok + t) * D_MODEL + colQ + k] = f2bf(qv * egsp);
        unsigned short kbf = f2bf(bf2f(rawk[t * 128 + k]) * ieg);
        kt[t * 136 + k] = kbf;
        ktT[k * 40 + t] = kbf;
      }
      EGC[k] = __expf(g);
      gseg += g;
    } else {
      const int j = tid - 128;
#pragma unroll
      for (int i = 0; i < 4; ++i) {
        int f = j * 4 + i;  // 0..511 uint4s of rawv
        int t = f >> 4, v0 = (f & 15) * 8;
        u16x8 r8 = *(const u16x8*)&rawv[t * 128 + v0];
#pragma unroll
        for (int e = 0; e < 8; ++e) vT[(v0 + e) * 40 + t] = r8[e];
      }
    }
    __syncthreads();

    if (c + 1 < NCH) stage_chunk(c + 1);  // overlap next-chunk loads with MFMA phases

    // ---- PHASE B: intra-chunk attention A = q~ k~^T (masked) ----
    {
      const int tt = w >> 1, tpt = w & 1;
      if (tpt <= tt) {
        f32x4 aacc = {};
#pragma unroll
        for (int ks = 0; ks < 4; ++ks) {
          bf16x8 qa = *(const bf16x8*)&qt[(tt * 16 + lr) * 136 + ks * 32 + lg * 8];
          bf16x8 ka = *(const bf16x8*)&kt[(tpt * 16 + lr) * 136 + ks * 32 + lg * 8];
          aacc = __builtin_amdgcn_mfma_f32_16x16x32_bf16(qa, ka, aacc, 0, 0, 0);
        }
#pragma unroll
        for (int r = 0; r < 4; ++r) {
          int t = tt * 16 + lg * 4 + r;
          int tp = tpt * 16 + lr;
          Am[t * 40 + tp] = f2bf((tp <= t) ? aacc[r] : 0.f);
        }
      } else {  // w==1: upper tile is all zero
#pragma unroll
        for (int r = 0; r < 4; ++r) Am[(lg * 4 + r) * 40 + 16 + lr] = 0;
      }
    }
    __syncthreads();

    // ---- PHASE C: o = q~@S_old + A@v ; sacc = EGC*(sacc + k~^T@v) ----
    f32x4 oacc[2][2] = {};
#pragma unroll
    for (int ks = 0; ks < 4; ++ks) {
      bf16x8 qa0 = *(const bf16x8*)&qt[(lr) * 136 + ks * 32 + lg * 8];
      bf16x8 qa1 = *(const bf16x8*)&qt[(16 + lr) * 136 + ks * 32 + lg * 8];
#pragma unroll
      for (int vtl = 0; vtl < 2; ++vtl) {
        const int v = (2 * w + vtl) * 16 + lr;
        bf16x8 bh = *(const bf16x8*)&Shi[v * 136 + ks * 32 + lg * 8];
        bf16x8 bl = *(const bf16x8*)&Slo[v * 136 + ks * 32 + lg * 8];
        oacc[0][vtl] = __builtin_amdgcn_mfma_f32_16x16x32_bf16(qa0, bh, oacc[0][vtl], 0, 0, 0);
        oacc[0][vtl] = __builtin_amdgcn_mfma_f32_16x16x32_bf16(qa0, bl, oacc[0][vtl], 0, 0, 0);
        oacc[1][vtl] = __builtin_amdgcn_mfma_f32_16x16x32_bf16(qa1, bh, oacc[1][vtl], 0, 0, 0);
        oacc[1][vtl] = __builtin_amdgcn_mfma_f32_16x16x32_bf16(qa1, bl, oacc[1][vtl], 0, 0, 0);
      }
    }
    {
      bf16x8 am0 = *(const bf16x8*)&Am[(lr) * 40 + lg * 8];
      bf16x8 am1 = *(const bf16x8*)&Am[(16 + lr) * 40 + lg * 8];
#pragma unroll
      for (int vtl = 0; vtl < 2; ++vtl) {
        const int v = (2 * w + vtl) * 16 + lr;
        bf16x8 bv = *(const bf16x8*)&vT[v * 40 + lg * 8];
        oacc[0][vtl] = __builtin_amdgcn_mfma_f32_16x16x32_bf16(am0, bv, oacc[0][vtl], 0, 0, 0);
        oacc[1][vtl] = __builtin_amdgcn_mfma_f32_16x16x32_bf16(am1, bv, oacc[1][vtl], 0, 0, 0);
      }
    }
#pragma unroll
    for (int tt = 0; tt < 2; ++tt)
#pragma unroll
      for (int vtl = 0; vtl < 2; ++vtl) {
        const int v = (2 * w + vtl) * 16 + lr;
#pragma unroll
        for (int r = 0; r < 4; ++r)
          obuf[(ctok + tt * 16 + lg * 4 + r) * D_MODEL + colQ + v] = f2bf(oacc[tt][vtl][r]);
      }
    {
      bf16x8 ak0 = *(const bf16x8*)&ktT[(32 * w + lr) * 40 + lg * 8];
      bf16x8 ak1 = *(const bf16x8*)&ktT[(32 * w + 16 + lr) * 40 + lg * 8];
#pragma unroll
      for (int vt = 0; vt < 8; ++vt) {
        bf16x8 bv = *(const bf16x8*)&vT[(vt * 16 + lr) * 40 + lg * 8];
        sacc[0][vt] = __builtin_amdgcn_mfma_f32_16x16x32_bf16(ak0, bv, sacc[0][vt], 0, 0, 0);
        sacc[1][vt] = __builtin_amdgcn_mfma_f32_16x16x32_bf16(ak1, bv, sacc[1][vt], 0, 0, 0);
      }
      f32x4 eg0 = *(const f32x4*)&EGC[32 * w + lg * 4];
      f32x4 eg1 = *(const f32x4*)&EGC[32 * w + 16 + lg * 4];
#pragma unroll
      for (int vt = 0; vt < 8; ++vt) {
        sacc[0][vt] *= eg0;
        sacc[1][vt] *= eg1;
      }
    }
  }

  // ---- epilogue: write segment summary dS ([v][k] f32) and decay ----
  const size_t dsbase = (((size_t)(b * NH + h) * NSEG + seg) * 128) * 128;
#pragma unroll
  for (int ktl = 0; ktl < 2; ++ktl) {
    const int k0 = 32 * w + ktl * 16 + lg * 4;
#pragma unroll
    for (int vt = 0; vt < 8; ++vt) {
      const int v = vt * 16 + lr;
      float4 st;
      st.x = sacc[ktl][vt][0]; st.y = sacc[ktl][vt][1];
      st.z = sacc[ktl][vt][2]; st.w = sacc[ktl][vt][3];
      *(float4*)&dS[dsbase + (size_t)v * 128 + k0] = st;
    }
  }
  if (tid < 128) Dseg[((size_t)(b * NH + h) * NSEG + seg) * 128 + tid] = __expf(gseg);
}

// =====================================================================
// Pass 2: segment scan. Sinit[0]=0; Sinit[s+1] = Dseg[s]*Sinit[s] + dS[s].
// Overwrites dS IN PLACE with packed (hi<<16|lo) bf16 Sinit per segment.
// grid (8, NH, B).
// =====================================================================
__global__ __launch_bounds__(256) void gla_scan(float* dS, const float* __restrict__ Dseg) {
  unsigned int* Spk = (unsigned int*)dS;
  const int tid = threadIdx.x;
  const int vs = blockIdx.x, h = blockIdx.y, b = blockIdx.z;
  const int v = vs * 16 + (tid >> 4);
  const int k0 = (tid & 15) * 8;
  const size_t bh = (size_t)b * NH + h;
  float s[8];
#pragma unroll
  for (int j = 0; j < 8; ++j) s[j] = 0.f;

  for (int sg = 0; sg < NSEG; ++sg) {
    const size_t base = ((bh * NSEG + sg) * 128 + v) * 128 + k0;
    float4 x0 = *(const float4*)&dS[base];
    float4 x1 = *(const float4*)&dS[base + 4];
    const size_t dbase = (bh * NSEG + sg) * 128 + k0;
    float4 d0 = *(const float4*)&Dseg[dbase];
    float4 d1 = *(const float4*)&Dseg[dbase + 4];

    uint4 p0, p1;
    p0.x = packhl(s[0]); p0.y = packhl(s[1]); p0.z = packhl(s[2]); p0.w = packhl(s[3]);
    p1.x = packhl(s[4]); p1.y = packhl(s[5]); p1.z = packhl(s[6]); p1.w = packhl(s[7]);
    *(uint4*)&Spk[base] = p0;
    *(uint4*)&Spk[base + 4] = p1;

    s[0] = d0.x * s[0] + x0.x; s[1] = d0.y * s[1] + x0.y;
    s[2] = d0.z * s[2] + x0.z; s[3] = d0.w * s[3] + x0.w;
    s[4] = d1.x * s[4] + x1.x; s[5] = d1.y * s[5] + x1.y;
    s[6] = d1.z * s[6] + x1.z; s[7] = d1.w * s[7] + x1.w;
  }
}

// =====================================================================
// Pass 3: o += qhat @ Sinit (per segment). grid (NSEG, NH, B). LDS 69.6 KB.
// MFMA C-operand initialized directly from obuf (fused RMW, no LDS staging).
// =====================================================================
__global__ __launch_bounds__(256) void gla_corr(const unsigned short* __restrict__ qhat,
                                                const unsigned int* __restrict__ Spk,
                                                unsigned short* __restrict__ obuf) {
  __shared__ __align__(16) unsigned short Sh[128 * 136];
  __shared__ __align__(16) unsigned short Sl[128 * 136];
  const int tid = threadIdx.x;
  const int lane = tid & 63, w = tid >> 6;
  const int lr = lane & 15, lg = lane >> 4;
  const int seg = blockIdx.x, h = blockIdx.y, b = blockIdx.z;
  const int colQ = h * DKH;
  const size_t segtok = (size_t)b * S_LEN + (size_t)seg * SEG;
  const size_t sbase = (((size_t)(b * NH + h) * NSEG + seg) * 128) * 128;

  // stage + unpack Sinit hi/lo into padded LDS
#pragma unroll
  for (int i = 0; i < 16; ++i) {
    int f = tid + i * 256;                 // 4096 uint4s over [v][k]
    int v = f >> 5, k0 = (f & 31) * 4;
    uint4 p = *(const uint4*)&Spk[sbase + (size_t)v * 128 + k0];
    u16x4 hv, lv;
    hv[0] = (unsigned short)(p.x >> 16); lv[0] = (unsigned short)(p.x & 0xffff);
    hv[1] = (unsigned short)(p.y >> 16); lv[1] = (unsigned short)(p.y & 0xffff);
    hv[2] = (unsigned short)(p.z >> 16); lv[2] = (unsigned short)(p.z & 0xffff);
    hv[3] = (unsigned short)(p.w >> 16); lv[3] = (unsigned short)(p.w & 0xffff);
    *(u16x4*)&Sh[v * 136 + k0] = hv;
    *(u16x4*)&Sl[v * 136 + k0] = lv;
  }
  __syncthreads();

  for (int nt = 0; nt < 4; ++nt) {
    const int ttile = w * 4 + nt;
    const int t = ttile * 16 + lr;
    f32x4 acc8[8];
#pragma unroll
    for (int vt = 0; vt < 8; ++vt) {
      u16x4 c4 = *(const u16x4*)&obuf[(segtok + t) * D_MODEL + colQ + vt * 16 + lg * 4];
      acc8[vt][0] = bf2f(c4[0]); acc8[vt][1] = bf2f(c4[1]);
      acc8[vt][2] = bf2f(c4[2]); acc8[vt][3] = bf2f(c4[3]);
    }
#pragma unroll
    for (int ks = 0; ks < 4; ++ks) {
      bf16x8 bq = *(const bf16x8*)&qhat[(segtok + t) * D_MODEL + colQ + ks * 32 + lg * 8];
#pragma unroll
      for (int vt = 0; vt < 8; ++vt) {
        bf16x8 ah = *(const bf16x8*)&Sh[(vt * 16 + lr) * 136 + ks * 32 + lg * 8];
        bf16x8 al = *(const bf16x8*)&Sl[(vt * 16 + lr) * 136 + ks * 32 + lg * 8];
        acc8[vt] = __builtin_amdgcn_mfma_f32_16x16x32_bf16(ah, bq, acc8[vt], 0, 0, 0);
        acc8[vt] = __builtin_amdgcn_mfma_f32_16x16x32_bf16(al, bq, acc8[vt], 0, 0, 0);
      }
    }
#pragma unroll
    for (int vt = 0; vt < 8; ++vt) {
      u16x4 pk;
#pragma unroll
      for (int r = 0; r < 4; ++r) pk[r] = f2bf(acc8[vt][r]);
      *(u16x4*)&obuf[(segtok + t) * D_MODEL + colQ + vt * 16 + lg * 4] = pk;
    }
  }
}

// ---------------- launch ----------------
extern "C" void kernel_launch(void* const* d_in, const int* in_sizes, int n_in,
                              void* d_out, int out_size, void* d_ws, size_t ws_size,
                              hipStream_t stream) {
  const float* x = (const float*)d_in[0];
  const float* W[5] = {(const float*)d_in[1], (const float*)d_in[2], (const float*)d_in[3],
                       (const float*)d_in[4], (const float*)d_in[5]};
  float* out = (float*)d_out;
  char* ws = (char*)d_ws;

  const size_t XBN = (size_t)B_SZ * S_LEN * D_MODEL;           // 16,777,216
  const size_t DD = (size_t)D_MODEL * D_MODEL;                  // 4,194,304
  const size_t NSTATE = (size_t)B_SZ * NH * NSEG * 128 * 128;   // 8,388,608

  // Workspace layout: 243.53 MB total (round-3's proven footprint)
  size_t off = 0;
  unsigned short* xb = (unsigned short*)(ws + off); off += XBN * 2;   // x bf16; later obuf
  unsigned short* Wt = (unsigned short*)(ws + off); off += 5 * DD * 2;
  unsigned short* qb = (unsigned short*)(ws + off); off += XBN * 2;   // q; later qhat (aliased)
  unsigned short* kb = (unsigned short*)(ws + off); off += XBN * 2;
  unsigned short* vb = (unsigned short*)(ws + off); off += XBN * 2;
  unsigned short* gkb = (unsigned short*)(ws + off); off += XBN * 2;  // gk bf16
  float* dS = (float*)(ws + off); off += NSTATE * 4;                  // later packed Sinit
  float* Dsg = (float*)(ws + off); off += (size_t)B_SZ * NH * NSEG * 128 * 4;
  unsigned short* obuf = xb;

  cast_bf16_kernel<<<dim3((unsigned)(XBN / 8 / 256)), dim3(256), 0, stream>>>(x, xb, (int)(XBN / 8));
  for (int i = 0; i < 5; ++i)
    transpose_cast_kernel<<<dim3(32, 32), dim3(256), 0, stream>>>(W[i], Wt + (size_t)i * DD);

  dim3 gg(GEMM_N / 256, GEMM_M / 256);   // (8, 32) = 256 blocks = 1/CU
  gemm256<1><<<gg, 512, 0, stream>>>(xb, Wt + 0 * DD, (void*)qb);   // q (scaled)
  gemm256<0><<<gg, 512, 0, stream>>>(xb, Wt + 1 * DD, (void*)kb);   // k
  gemm256<0><<<gg, 512, 0, stream>>>(xb, Wt + 2 * DD, (void*)vb);   // v
  gemm256<2><<<gg, 512, 0, stream>>>(xb, Wt + 3 * DD, (void*)gkb);  // gk (bf16)

  gla_seg1<<<dim3(NSEG, NH, B_SZ), 256, 0, stream>>>(qb, kb, vb, gkb, qb /*qhat*/, obuf, dS, Dsg);
  gla_scan<<<dim3(8, NH, B_SZ), 256, 0, stream>>>(dS, Dsg);
  gla_corr<<<dim3(NSEG, NH, B_SZ), 256, 0, stream>>>(qb /*qhat*/, (const unsigned int*)dS, obuf);

  gemm256<3><<<gg, 512, 0, stream>>>(obuf, Wt + 4 * DD, (void*)out);  // final projection
}